// Round 2
// baseline (195.491 us; speedup 1.0000x reference)
//
#include <hip/hip_runtime.h>
#include <hip/hip_fp16.h>

#define N_SEQ 8192
#define E_DIM 768
#define D_OUT 64
#define PADK 68                       // 64 + 4 pad -> 136B rows: 8B-aligned, 2-way (free) banks
#define SCALE_LOG2 0.18033688011112042f   // 1/(8*ln2): fold softmax scale + log2e into Q

typedef __attribute__((ext_vector_type(8)))  short s16x8;
typedef __attribute__((ext_vector_type(16))) float f32x16;

static __device__ __forceinline__ unsigned short f2bf(float f) {
    union { float f; unsigned int u; } v; v.f = f;
    unsigned int r = v.u + 0x7FFFu + ((v.u >> 16) & 1u);   // RNE
    return (unsigned short)(r >> 16);
}
static __device__ __forceinline__ float bf2f(unsigned short h) {
    union { float f; unsigned int u; } v; v.u = ((unsigned int)h) << 16; return v.f;
}
// packed f16 max on int-punned half2 (ROCm header lacks __hmax2 on this path)
static __device__ __forceinline__ int pkmax_f16(int a, int b) {
    int d;
    asm("v_pk_max_f16 %0, %1, %2" : "=v"(d) : "v"(a), "v"(b));
    return d;
}
// 16B global fragment load (8 contiguous bf16)
static __device__ __forceinline__ s16x8 gfrag(const unsigned short* p) {
    union { uint4 u; s16x8 s; } r; r.u = *(const uint4*)p; return r.s;
}
// 16B LDS fragment load, 8B-aligned (two b64 reads)
static __device__ __forceinline__ s16x8 ldsfrag(const unsigned short* p) {
    union { uint2 u[2]; s16x8 s; } r;
    r.u[0] = *(const uint2*)(p);
    r.u[1] = *(const uint2*)(p + 4);
    return r.s;
}
static __device__ __forceinline__ void st32(unsigned short* d, uint4 a, uint4 b) {
    uint2* p = (uint2*)d;
    p[0] = make_uint2(a.x, a.y); p[1] = make_uint2(a.z, a.w);
    p[2] = make_uint2(b.x, b.y); p[3] = make_uint2(b.z, b.w);
}

// ---------------- Kernel 1: W -> Wt (transposed, bf16 hi/lo) -----------------
__global__ __launch_bounds__(256) void prep_w(const float* __restrict__ WQ,
                                              const float* __restrict__ WK,
                                              const float* __restrict__ WV,
                                              unsigned short* __restrict__ Wthi,
                                              unsigned short* __restrict__ Wtlo) {
    int idx = blockIdx.x * 256 + threadIdx.x;          // 192*768 total
    if (idx >= 192 * E_DIM) return;
    int n = idx / E_DIM;
    int k = idx - n * E_DIM;
    float v;
    if (n < 64)       v = WQ[k * 64 + n];
    else if (n < 128) v = WK[k * 64 + (n - 64)];
    else              v = WV[k * 64 + (n - 128)];
    unsigned short hb = f2bf(v);
    Wthi[idx] = hb;
    Wtlo[idx] = f2bf(v - bf2f(hb));
}

// ---------------- Kernel 2: QKV projection (split-bf16 MFMA) -----------------
// C = X[8192x768] @ W[768x192]; wave tiles 32x32, 1536 wave-tasks.
__global__ __launch_bounds__(256, 4) void proj_qkv(const float* __restrict__ X,
                                                   const unsigned short* __restrict__ Wthi,
                                                   const unsigned short* __restrict__ Wtlo,
                                                   unsigned short* __restrict__ Qhi,
                                                   unsigned short* __restrict__ Qlo,
                                                   unsigned short* __restrict__ Khi,
                                                   unsigned short* __restrict__ Klo,
                                                   unsigned short* __restrict__ Vt) {
    int tid  = threadIdx.x;
    int wv   = tid >> 6;
    int lane = tid & 63;
    int id   = blockIdx.x * 4 + wv;          // 0..1535
    int mt   = id / 6;
    int nt   = id - mt * 6;
    int m0 = mt * 32, n0 = nt * 32;
    int lrow = lane & 31, lh = lane >> 5;

    f32x16 acc;
    #pragma unroll
    for (int i = 0; i < 16; ++i) acc[i] = 0.f;

    const float* xbase = X + (size_t)(m0 + lrow) * E_DIM;
    const unsigned short* wh = Wthi + (size_t)(n0 + lrow) * E_DIM;
    const unsigned short* wl = Wtlo + (size_t)(n0 + lrow) * E_DIM;

    for (int ks = 0; ks < E_DIM / 16; ++ks) {
        int kb = ks * 16 + lh * 8;
        float xv[8];
        *(float4*)(xv)     = *(const float4*)(xbase + kb);
        *(float4*)(xv + 4) = *(const float4*)(xbase + kb + 4);
        s16x8 ah, al;
        #pragma unroll
        for (int j = 0; j < 8; ++j) {
            unsigned short hb = f2bf(xv[j]);
            ah[j] = (short)hb;
            al[j] = (short)f2bf(xv[j] - bf2f(hb));
        }
        s16x8 bh = gfrag(wh + kb);
        s16x8 bl = gfrag(wl + kb);
        acc = __builtin_amdgcn_mfma_f32_32x32x16_bf16(ah, bh, acc, 0, 0, 0);
        acc = __builtin_amdgcn_mfma_f32_32x32x16_bf16(ah, bl, acc, 0, 0, 0);
        acc = __builtin_amdgcn_mfma_f32_32x32x16_bf16(al, bh, acc, 0, 0, 0);
    }

    // Epilogue: C/D layout col=lane&31, row=(r&3)+8*(r>>2)+4*lh  [verified m74/m101]
    if (n0 < 64) {                       // Q: scale by 1/(8 ln2), split hi/lo
        #pragma unroll
        for (int r = 0; r < 16; ++r) {
            int row = (r & 3) + 8 * (r >> 2) + 4 * lh;
            int grow = m0 + row, gcol = n0 + lrow;
            float q = acc[r] * SCALE_LOG2;
            unsigned short hb = f2bf(q);
            Qhi[(size_t)grow * 64 + gcol] = hb;
            Qlo[(size_t)grow * 64 + gcol] = f2bf(q - bf2f(hb));
        }
    } else if (n0 < 128) {               // K: split hi/lo
        #pragma unroll
        for (int r = 0; r < 16; ++r) {
            int row = (r & 3) + 8 * (r >> 2) + 4 * lh;
            int grow = m0 + row, gcol = n0 + lrow - 64;
            float v = acc[r];
            unsigned short hb = f2bf(v);
            Khi[(size_t)grow * 64 + gcol] = hb;
            Klo[(size_t)grow * 64 + gcol] = f2bf(v - bf2f(hb));
        }
    } else {                             // V: store transposed bf16 (hi only)
        #pragma unroll
        for (int r = 0; r < 16; ++r) {
            int row = (r & 3) + 8 * (r >> 2) + 4 * lh;
            int grow = m0 + row, gcol = n0 + lrow - 128;
            Vt[(size_t)gcol * N_SEQ + grow] = f2bf(acc[r]);
        }
    }
}

// ---------------- Kernel 3: flash attention (split-K over KV) ----------------
// grid (nsplit, 64); block 256 = 4 waves, each wave owns 32 Q-rows.
__global__ __launch_bounds__(256, 2) void attn(const unsigned short* __restrict__ Qhi,
                                               const unsigned short* __restrict__ Qlo,
                                               const unsigned short* __restrict__ Khi,
                                               const unsigned short* __restrict__ Klo,
                                               const unsigned short* __restrict__ Vt,
                                               float* __restrict__ Opart,
                                               float* __restrict__ mpart,
                                               float* __restrict__ lpart,
                                               int chunk) {
    __shared__ unsigned short sKh[64 * PADK];
    __shared__ unsigned short sKl[64 * PADK];
    __shared__ unsigned short sV [64 * PADK];    // [d][key]
    __shared__ unsigned short sP [4][32 * PADK]; // per-wave P, [m][key]

    int tid = threadIdx.x, wv = tid >> 6, lane = tid & 63;
    int lrow = lane & 31, lh = lane >> 5;
    int c = blockIdx.x, qb = blockIdx.y;
    int q0 = qb * 128 + wv * 32;

    // Q fragments (whole D=64) resident in registers
    s16x8 qh[4], ql[4];
    #pragma unroll
    for (int ks = 0; ks < 4; ++ks) {
        int kb = ks * 16 + lh * 8;
        qh[ks] = gfrag(Qhi + (size_t)(q0 + lrow) * 64 + kb);
        ql[ks] = gfrag(Qlo + (size_t)(q0 + lrow) * 64 + kb);
    }

    f32x16 O0, O1, La;
    #pragma unroll
    for (int i = 0; i < 16; ++i) { O0[i] = 0.f; O1[i] = 0.f; La[i] = 0.f; }
    float mrow[16];
    #pragma unroll
    for (int r = 0; r < 16; ++r) mrow[r] = -1e30f;
    s16x8 ones;
    #pragma unroll
    for (int j = 0; j < 8; ++j) ones[j] = (short)0x3F80;   // bf16 1.0

    int steps = chunk >> 6;
    int srow = tid >> 2, sseg = tid & 3;    // staging: 64 rows x 4 segs x 16 elems

    for (int it = 0; it < steps; ++it) {
        int j0 = c * chunk + it * 64;
        __syncthreads();
        {   // stage K hi/lo tiles [64 keys][64 d] and V^T tile [64 d][64 keys]
            const uint4* ps = (const uint4*)(Khi + ((size_t)(j0 + srow) * 64 + sseg * 16));
            st32(sKh + srow * PADK + sseg * 16, ps[0], ps[1]);
            ps = (const uint4*)(Klo + ((size_t)(j0 + srow) * 64 + sseg * 16));
            st32(sKl + srow * PADK + sseg * 16, ps[0], ps[1]);
            ps = (const uint4*)(Vt + ((size_t)srow * N_SEQ + j0 + sseg * 16));
            st32(sV + srow * PADK + sseg * 16, ps[0], ps[1]);
        }
        __syncthreads();

        // S = Qs @ K^T  (3-term split-bf16)
        f32x16 s0, s1;
        #pragma unroll
        for (int i = 0; i < 16; ++i) { s0[i] = 0.f; s1[i] = 0.f; }
        #pragma unroll
        for (int ks = 0; ks < 4; ++ks) {
            int kb = ks * 16 + lh * 8;
            s16x8 b0h = ldsfrag(sKh + (size_t)lrow * PADK + kb);
            s16x8 b0l = ldsfrag(sKl + (size_t)lrow * PADK + kb);
            s0 = __builtin_amdgcn_mfma_f32_32x32x16_bf16(qh[ks], b0h, s0, 0, 0, 0);
            s0 = __builtin_amdgcn_mfma_f32_32x32x16_bf16(qh[ks], b0l, s0, 0, 0, 0);
            s0 = __builtin_amdgcn_mfma_f32_32x32x16_bf16(ql[ks], b0h, s0, 0, 0, 0);
            s16x8 b1h = ldsfrag(sKh + (size_t)(32 + lrow) * PADK + kb);
            s16x8 b1l = ldsfrag(sKl + (size_t)(32 + lrow) * PADK + kb);
            s1 = __builtin_amdgcn_mfma_f32_32x32x16_bf16(qh[ks], b1h, s1, 0, 0, 0);
            s1 = __builtin_amdgcn_mfma_f32_32x32x16_bf16(qh[ks], b1l, s1, 0, 0, 0);
            s1 = __builtin_amdgcn_mfma_f32_32x32x16_bf16(ql[ks], b1h, s1, 0, 0, 0);
        }

        // row max across 32 key-cols (lanes) via packed-f16 butterfly
        union H2I { __half2 h2; int i; } hmx[8];
        #pragma unroll
        for (int j = 0; j < 8; ++j)
            hmx[j].h2 = __floats2half2_rn(fmaxf(s0[2 * j],     s1[2 * j]),
                                          fmaxf(s0[2 * j + 1], s1[2 * j + 1]));
        #pragma unroll
        for (int msk = 1; msk < 32; msk <<= 1) {
            #pragma unroll
            for (int j = 0; j < 8; ++j) {
                int o = __shfl_xor(hmx[j].i, msk, 64);
                hmx[j].i = pkmax_f16(hmx[j].i, o);
            }
        }
        float alf[16];
        #pragma unroll
        for (int j = 0; j < 8; ++j) {
            float rm0 = __low2float(hmx[j].h2), rm1 = __high2float(hmx[j].h2);
            int r = 2 * j;
            float mn = fmaxf(mrow[r], rm0);
            alf[r] = exp2f(mrow[r] - mn); mrow[r] = mn;
            r = 2 * j + 1;
            mn = fmaxf(mrow[r], rm1);
            alf[r] = exp2f(mrow[r] - mn); mrow[r] = mn;
        }

        // P = exp2(S - m); rescale O,l; write P (bf16) to per-wave LDS [m][key]
        unsigned short* pp = sP[wv];
        #pragma unroll
        for (int r = 0; r < 16; ++r) {
            float p0 = exp2f(s0[r] - mrow[r]);
            float p1 = exp2f(s1[r] - mrow[r]);
            O0[r] *= alf[r]; O1[r] *= alf[r]; La[r] *= alf[r];
            int row = (r & 3) + 8 * (r >> 2) + 4 * lh;
            pp[row * PADK + lrow]      = f2bf(p0);
            pp[row * PADK + 32 + lrow] = f2bf(p1);
        }

        // O += P @ V ; l += P @ 1 (ones-column MFMA replaces shuffle row-sums)
        #pragma unroll
        for (int ks = 0; ks < 4; ++ks) {
            int kb = ks * 16 + lh * 8;
            s16x8 a  = ldsfrag(pp + (size_t)lrow * PADK + kb);
            s16x8 b0 = ldsfrag(sV + (size_t)lrow * PADK + kb);
            s16x8 b1 = ldsfrag(sV + (size_t)(32 + lrow) * PADK + kb);
            O0 = __builtin_amdgcn_mfma_f32_32x32x16_bf16(a, b0,   O0, 0, 0, 0);
            O1 = __builtin_amdgcn_mfma_f32_32x32x16_bf16(a, b1,   O1, 0, 0, 0);
            La = __builtin_amdgcn_mfma_f32_32x32x16_bf16(a, ones, La, 0, 0, 0);
        }
    }

    // store partials
    #pragma unroll
    for (int r = 0; r < 16; ++r) {
        int row = (r & 3) + 8 * (r >> 2) + 4 * lh;
        int grow = q0 + row;
        size_t ob = ((size_t)c * N_SEQ + grow) * 64;
        Opart[ob + lrow]      = O0[r];
        Opart[ob + 32 + lrow] = O1[r];
        if (lrow == 0) {
            mpart[c * N_SEQ + grow] = mrow[r];
            lpart[c * N_SEQ + grow] = La[r];
        }
    }
}

// ---------------- Kernel 4: combine split-K partials -------------------------
__global__ __launch_bounds__(256) void combine(const float* __restrict__ Opart,
                                               const float* __restrict__ mpart,
                                               const float* __restrict__ lpart,
                                               float* __restrict__ out,
                                               int nsplit) {
    int idx = blockIdx.x * 256 + threadIdx.x;    // N_SEQ*64
    int row = idx >> 6, d = idx & 63;
    float M = -1e30f;
    for (int c = 0; c < nsplit; ++c) M = fmaxf(M, mpart[c * N_SEQ + row]);
    float num = 0.f, den = 0.f;
    for (int c = 0; c < nsplit; ++c) {
        float w = exp2f(mpart[c * N_SEQ + row] - M);
        den += w * lpart[c * N_SEQ + row];
        num += w * Opart[((size_t)c * N_SEQ + row) * 64 + d];
    }
    out[idx] = num / den;
}

extern "C" void kernel_launch(void* const* d_in, const int* in_sizes, int n_in,
                              void* d_out, int out_size, void* d_ws, size_t ws_size,
                              hipStream_t stream) {
    const float* X  = (const float*)d_in[0];
    const float* WQ = (const float*)d_in[1];
    const float* WK = (const float*)d_in[2];
    const float* WV = (const float*)d_in[3];
    float* out = (float*)d_out;

    // workspace carve
    const size_t szQK = (size_t)N_SEQ * 64 * 2;      // 1 MB each (bf16)
    const size_t szW  = (size_t)192 * E_DIM * 2;     // 288 KB each
    char* p = (char*)d_ws;
    unsigned short* Qhi = (unsigned short*)p; p += szQK;
    unsigned short* Qlo = (unsigned short*)p; p += szQK;
    unsigned short* Khi = (unsigned short*)p; p += szQK;
    unsigned short* Klo = (unsigned short*)p; p += szQK;
    unsigned short* Vt  = (unsigned short*)p; p += szQK;
    unsigned short* Wthi = (unsigned short*)p; p += szW;
    unsigned short* Wtlo = (unsigned short*)p; p += szW;
    size_t base = (size_t)(p - (char*)d_ws);
    size_t per  = (size_t)N_SEQ * 64 * 4 + 2 * (size_t)N_SEQ * 4;  // Opart + m + l per split
    int nsplit = 8;
    while (nsplit > 1 && base + (size_t)nsplit * per > ws_size) nsplit >>= 1;
    float* mpart = (float*)p; p += (size_t)nsplit * N_SEQ * 4;
    float* lpart = (float*)p; p += (size_t)nsplit * N_SEQ * 4;
    float* Opart = (float*)p;

    int chunk = N_SEQ / nsplit;

    prep_w<<<(192 * E_DIM + 255) / 256, 256, 0, stream>>>(WQ, WK, WV, Wthi, Wtlo);
    proj_qkv<<<384, 256, 0, stream>>>(X, Wthi, Wtlo, Qhi, Qlo, Khi, Klo, Vt);
    attn<<<dim3(nsplit, N_SEQ / 128), 256, 0, stream>>>(Qhi, Qlo, Khi, Klo, Vt,
                                                        Opart, mpart, lpart, chunk);
    combine<<<(N_SEQ * 64 + 255) / 256, 256, 0, stream>>>(Opart, mpart, lpart, out, nsplit);
}